// Round 1
// baseline (526.967 us; speedup 1.0000x reference)
//
#include <hip/hip_runtime.h>
#include <math.h>

typedef __attribute__((ext_vector_type(8))) short bf16x8;
typedef __attribute__((ext_vector_type(4))) float f32x4;

__device__ __forceinline__ ushort f2bf(float f) {
  union { float f; unsigned u; } v; v.f = f;
  unsigned u = v.u + 0x7FFFu + ((v.u >> 16) & 1u);
  return (ushort)(u >> 16);
}
__device__ __forceinline__ float bf2f(ushort h) {
  union { unsigned u; float f; } v; v.u = ((unsigned)h) << 16;
  return v.f;
}
__device__ __forceinline__ void gload_lds16(const ushort* g, ushort* l) {
  __builtin_amdgcn_global_load_lds((const __attribute__((address_space(1))) void*)g,
                                   (__attribute__((address_space(3))) void*)l, 16, 0, 0);
}

// ---------------------------------------------------------------- prep: casts + packing
__global__ __launch_bounds__(256) void prep_kernel(
    const float* __restrict__ hs, const float* __restrict__ qw,
    const float* __restrict__ kw, const float* __restrict__ vw,
    const float* __restrict__ ow, const float* __restrict__ qb,
    const float* __restrict__ kb, const float* __restrict__ vb,
    ushort* __restrict__ hs_b, ushort* __restrict__ qkvw_b,
    ushort* __restrict__ ow_b, float* __restrict__ qkvb)
{
  const int idx = blockIdx.x * 256 + threadIdx.x;
  const int stride = gridDim.x * 256;
  const float4* hs4 = (const float4*)hs;
  const float4* qw4 = (const float4*)qw;
  const float4* kw4 = (const float4*)kw;
  const float4* vw4 = (const float4*)vw;
  const float4* ow4 = (const float4*)ow;
  ushort4* hsb4 = (ushort4*)hs_b;
  ushort4* qkvwb4 = (ushort4*)qkvw_b;
  ushort4* owb4 = (ushort4*)ow_b;

  for (int i = idx; i < 2097152; i += stride) {           // hidden 8388608
    float4 v = hs4[i];
    ushort4 o; o.x=f2bf(v.x); o.y=f2bf(v.y); o.z=f2bf(v.z); o.w=f2bf(v.w);
    hsb4[i] = o;
  }
  for (int i = idx; i < 1048576; i += stride) {           // q_w 4194304
    float4 v = qw4[i];
    ushort4 o; o.x=f2bf(v.x); o.y=f2bf(v.y); o.z=f2bf(v.z); o.w=f2bf(v.w);
    qkvwb4[i] = o;
  }
  for (int i = idx; i < 262144; i += stride) {            // k_w 1048576
    float4 v = kw4[i];
    ushort4 o; o.x=f2bf(v.x); o.y=f2bf(v.y); o.z=f2bf(v.z); o.w=f2bf(v.w);
    qkvwb4[1048576 + i] = o;
  }
  for (int i = idx; i < 262144; i += stride) {            // v_w
    float4 v = vw4[i];
    ushort4 o; o.x=f2bf(v.x); o.y=f2bf(v.y); o.z=f2bf(v.z); o.w=f2bf(v.w);
    qkvwb4[1310720 + i] = o;
  }
  for (int i = idx; i < 1048576; i += stride) {           // o_w 4194304
    float4 v = ow4[i];
    ushort4 o; o.x=f2bf(v.x); o.y=f2bf(v.y); o.z=f2bf(v.z); o.w=f2bf(v.w);
    owb4[i] = o;
  }
  for (int i = idx; i < 3072; i += stride)
    qkvb[i] = (i < 2048) ? qb[i] : (i < 2560 ? kb[i - 2048] : vb[i - 2560]);
}

// ---------------------------------------------------------------- GEMM: C = A(MxK) * Bw(NxK)^T + bias
// m97-style: 128x128 tile, BK=32, global_load_lds(16B), 16x16x32 bf16 MFMA, 4 waves 2x2.
template<int BF16OUT>
__global__ __launch_bounds__(256) void gemm_bt(
    const ushort* __restrict__ A, const ushort* __restrict__ Bw,
    const float* __restrict__ bias, void* __restrict__ Cout,
    int M, int N, int K)
{
  __shared__ ushort As[128 * 32];
  __shared__ ushort Bs[128 * 32];
  const int t = threadIdx.x;
  const int wv = t >> 6;
  const int lane = t & 63;
  const int qd = lane >> 4, ln = lane & 15;
  const long row0 = (long)blockIdx.x * 128, col0 = (long)blockIdx.y * 128;
  const int wm = (wv >> 1) * 64, wn = (wv & 1) * 64;

  f32x4 acc[4][4];
#pragma unroll
  for (int i = 0; i < 4; i++)
#pragma unroll
    for (int j = 0; j < 4; j++) acc[i][j] = (f32x4){0.f, 0.f, 0.f, 0.f};

  const ushort* gA = A + (row0 + (t >> 2)) * (long)K + (t & 3) * 8;
  const ushort* gB = Bw + (col0 + (t >> 2)) * (long)K + (t & 3) * 8;
  ushort* lA = &As[wv * 512];
  ushort* lB = &Bs[wv * 512];
  const long K64 = 64l * K;

  for (int kt = 0; kt < K; kt += 32) {
    __syncthreads();
    gload_lds16(gA + kt,        lA);
    gload_lds16(gA + kt + K64,  lA + 2048);
    gload_lds16(gB + kt,        lB);
    gload_lds16(gB + kt + K64,  lB + 2048);
    __syncthreads();
    bf16x8 af[4], bf[4];
#pragma unroll
    for (int mi = 0; mi < 4; mi++)
      af[mi] = *(const bf16x8*)&As[(wm + mi * 16 + ln) * 32 + qd * 8];
#pragma unroll
    for (int ni = 0; ni < 4; ni++)
      bf[ni] = *(const bf16x8*)&Bs[(wn + ni * 16 + ln) * 32 + qd * 8];
#pragma unroll
    for (int mi = 0; mi < 4; mi++)
#pragma unroll
      for (int ni = 0; ni < 4; ni++)
        acc[mi][ni] = __builtin_amdgcn_mfma_f32_16x16x32_bf16(af[mi], bf[ni], acc[mi][ni], 0, 0, 0);
  }

  float bv[4];
#pragma unroll
  for (int ni = 0; ni < 4; ni++) bv[ni] = bias[col0 + wn + ni * 16 + ln];
#pragma unroll
  for (int mi = 0; mi < 4; mi++)
#pragma unroll
    for (int ni = 0; ni < 4; ni++)
#pragma unroll
      for (int r = 0; r < 4; r++) {
        long row = row0 + wm + mi * 16 + qd * 4 + r;
        long col = col0 + wn + ni * 16 + ln;
        float v = acc[mi][ni][r] + bv[ni];
        if (BF16OUT) ((ushort*)Cout)[row * N + col] = f2bf(v);
        else         ((float*)Cout)[row * N + col] = v;
      }
}

// ---------------------------------------------------------------- RoPE in place on Q (heads 0..15) and K (heads 16..19)
__global__ __launch_bounds__(256) void rope_kernel(ushort* __restrict__ qkv)
{
  const int i = blockIdx.x * 256 + threadIdx.x;   // 4096 rows * 20 heads * 64 pairs
  if (i >= 5242880) return;
  const int pair = i & 63;
  const int head = (i >> 6) % 20;
  const int row  = (i >> 6) / 20;
  const int pos  = row & 2047;
  const int base = head < 16 ? head * 128 : 2048 + (head - 16) * 128;
  ushort* p = qkv + (long)row * 3072 + base + pair;
  const float v0 = bf2f(p[0]);
  const float v1 = bf2f(p[64]);
  const float inv = expf((float)pair * -0.14391156831212787f);  // theta^(-2i/128)
  const float ang = (float)pos * inv;
  const float c = cosf(ang), s = sinf(ang);
  p[0]  = f2bf(v0 * c - v1 * s);
  p[64] = f2bf(v1 * c + v0 * s);
}

// ---------------------------------------------------------------- flash attention, BM=64, BN=64, HD=128
__global__ __launch_bounds__(256) void flash_kernel(
    const ushort* __restrict__ qkv, ushort* __restrict__ ctx)
{
  __shared__ ushort Qs[64 * 136];   // padded stride 136 keeps b128 reads uniform & aligned
  __shared__ ushort Ks[64 * 136];
  __shared__ ushort Vts[128 * 68];  // V transposed: [d][p], stride 68, b64 reads
  __shared__ ushort Ps[64 * 68];

  const int t = threadIdx.x, wv = t >> 6, lane = t & 63;
  const int qd = lane >> 4, ln = lane & 15;
  const int q0 = blockIdx.x * 64;
  const int b = blockIdx.y >> 4, h = blockIdx.y & 15;
  const long rb = (long)b * 2048;
  const ushort* Qg = qkv + (rb + q0) * 3072 + h * 128;
  const ushort* Kg = qkv + rb * 3072 + 2048 + (h >> 2) * 128;
  const ushort* Vg = qkv + rb * 3072 + 2560 + (h >> 2) * 128;

  const int sr = t >> 4;          // 0..15
  const int sc = (t & 15) * 8;    // 0..120

#pragma unroll
  for (int i = 0; i < 4; i++) {
    int row = i * 16 + sr;
    *(uint4*)&Qs[row * 136 + sc] = *(const uint4*)(Qg + (long)row * 3072 + sc);
  }

  f32x4 oacc[8];
#pragma unroll
  for (int ni = 0; ni < 8; ni++) oacc[ni] = (f32x4){0.f, 0.f, 0.f, 0.f};
  float m_i[4] = {-INFINITY, -INFINITY, -INFINITY, -INFINITY};
  float l_i[4] = {0.f, 0.f, 0.f, 0.f};
  const float scale = 0.08838834764831845f;   // 1/sqrt(128)

  for (int kt = 0; kt < 2048; kt += 64) {
    __syncthreads();   // protect Ks/Vts (and Qs on first iter)
#pragma unroll
    for (int i = 0; i < 4; i++) {
      int row = i * 16 + sr;
      *(uint4*)&Ks[row * 136 + sc] = *(const uint4*)(Kg + (long)(kt + row) * 3072 + sc);
    }
#pragma unroll
    for (int i = 0; i < 4; i++) {
      int p = i * 16 + sr;
      union { uint4 q; ushort e[8]; } u;
      u.q = *(const uint4*)(Vg + (long)(kt + p) * 3072 + sc);
#pragma unroll
      for (int j = 0; j < 8; j++) Vts[(sc + j) * 68 + p] = u.e[j];
    }
    __syncthreads();

    // S = Q K^T (wave's 16 rows x 64 cols)
    f32x4 sacc[4];
#pragma unroll
    for (int ni = 0; ni < 4; ni++) sacc[ni] = (f32x4){0.f, 0.f, 0.f, 0.f};
#pragma unroll
    for (int ks = 0; ks < 4; ks++) {
      bf16x8 aq = *(const bf16x8*)&Qs[(wv * 16 + ln) * 136 + ks * 32 + qd * 8];
#pragma unroll
      for (int ni = 0; ni < 4; ni++) {
        bf16x8 bk = *(const bf16x8*)&Ks[(ni * 16 + ln) * 136 + ks * 32 + qd * 8];
        sacc[ni] = __builtin_amdgcn_mfma_f32_16x16x32_bf16(aq, bk, sacc[ni], 0, 0, 0);
      }
    }

    // online softmax (rows = qd*4+r, cols = ni*16+ln)
    float alpha[4];
#pragma unroll
    for (int r = 0; r < 4; r++) {
      float mx = -INFINITY;
#pragma unroll
      for (int ni = 0; ni < 4; ni++) {
        sacc[ni][r] *= scale;
        mx = fmaxf(mx, sacc[ni][r]);
      }
      mx = fmaxf(mx, __shfl_xor(mx, 1, 64));
      mx = fmaxf(mx, __shfl_xor(mx, 2, 64));
      mx = fmaxf(mx, __shfl_xor(mx, 4, 64));
      mx = fmaxf(mx, __shfl_xor(mx, 8, 64));
      float mn = fmaxf(m_i[r], mx);
      float al = __expf(m_i[r] - mn);
      float rs = 0.f;
#pragma unroll
      for (int ni = 0; ni < 4; ni++) {
        float pv = __expf(sacc[ni][r] - mn);
        sacc[ni][r] = pv;
        rs += pv;
      }
      rs += __shfl_xor(rs, 1, 64);
      rs += __shfl_xor(rs, 2, 64);
      rs += __shfl_xor(rs, 4, 64);
      rs += __shfl_xor(rs, 8, 64);
      l_i[r] = l_i[r] * al + rs;
      m_i[r] = mn;
      alpha[r] = al;
    }
#pragma unroll
    for (int ni = 0; ni < 8; ni++)
#pragma unroll
      for (int r = 0; r < 4; r++) oacc[ni][r] *= alpha[r];

    // P -> LDS (C-layout write, own wave rows only; A-layout read below)
#pragma unroll
    for (int ni = 0; ni < 4; ni++)
#pragma unroll
      for (int r = 0; r < 4; r++)
        Ps[(wv * 16 + qd * 4 + r) * 68 + ni * 16 + ln] = f2bf(sacc[ni][r]);

    // O += P V   (A = P 16x64, B = V 64x128 via Vts)
#pragma unroll
    for (int ks = 0; ks < 2; ks++) {
      const ushort* pa = &Ps[(wv * 16 + ln) * 68 + ks * 32 + qd * 8];
      short4 a0 = *(const short4*)pa;
      short4 a1 = *(const short4*)(pa + 4);
      bf16x8 ap = (bf16x8){a0.x, a0.y, a0.z, a0.w, a1.x, a1.y, a1.z, a1.w};
#pragma unroll
      for (int ni = 0; ni < 8; ni++) {
        const ushort* pb = &Vts[(ln + 16 * ni) * 68 + ks * 32 + qd * 8];
        short4 b0 = *(const short4*)pb;
        short4 b1 = *(const short4*)(pb + 4);
        bf16x8 bv = (bf16x8){b0.x, b0.y, b0.z, b0.w, b1.x, b1.y, b1.z, b1.w};
        oacc[ni] = __builtin_amdgcn_mfma_f32_16x16x32_bf16(ap, bv, oacc[ni], 0, 0, 0);
      }
    }
  }

  const long orow = rb + q0 + wv * 16;
#pragma unroll
  for (int ni = 0; ni < 8; ni++)
#pragma unroll
    for (int r = 0; r < 4; r++) {
      float v = oacc[ni][r] / (l_i[r] + 1e-10f);
      ctx[(orow + qd * 4 + r) * 2048 + h * 128 + ni * 16 + ln] = f2bf(v);
    }
}

// ---------------------------------------------------------------- launch
extern "C" void kernel_launch(void* const* d_in, const int* in_sizes, int n_in,
                              void* d_out, int out_size, void* d_ws, size_t ws_size,
                              hipStream_t stream)
{
  const float* hs = (const float*)d_in[0];
  const float* qw = (const float*)d_in[1];
  const float* qb = (const float*)d_in[2];
  const float* kw = (const float*)d_in[3];
  const float* kb = (const float*)d_in[4];
  const float* vw = (const float*)d_in[5];
  const float* vb = (const float*)d_in[6];
  const float* ow = (const float*)d_in[7];
  const float* ob = (const float*)d_in[8];

  char* ws = (char*)d_ws;
  ushort* hs_b   = (ushort*)(ws);                 // 16,777,216 B
  ushort* qkvw_b = (ushort*)(ws + 16777216);      // 12,582,912 B
  ushort* ow_b   = (ushort*)(ws + 29360128);      //  8,388,608 B
  float*  qkvb   = (float*) (ws + 37748736);      //     12,288 B
  ushort* qkvbuf = (ushort*)(ws + 37761024);      // 25,165,824 B
  ushort* ctx    = (ushort*)(ws + 62926848);      // 16,777,216 B  (total ~79.7 MB)

  prep_kernel<<<1024, 256, 0, stream>>>(hs, qw, kw, vw, ow, qb, kb, vb,
                                        hs_b, qkvw_b, ow_b, qkvb);
  gemm_bt<1><<<dim3(32, 24), 256, 0, stream>>>(hs_b, qkvw_b, qkvb, qkvbuf,
                                               4096, 3072, 2048);
  rope_kernel<<<20480, 256, 0, stream>>>(qkvbuf);
  flash_kernel<<<dim3(32, 32), 256, 0, stream>>>(qkvbuf, ctx);
  gemm_bt<0><<<dim3(32, 16), 256, 0, stream>>>(ctx, ow_b, ob, d_out,
                                               4096, 2048, 2048);
}

// Round 2
// 425.141 us; speedup vs baseline: 1.2395x; 1.2395x over previous
//
#include <hip/hip_runtime.h>
#include <math.h>

typedef __attribute__((ext_vector_type(8))) short bf16x8;
typedef __attribute__((ext_vector_type(4))) float f32x4;

__device__ __forceinline__ ushort f2bf(float f) {
  union { float f; unsigned u; } v; v.f = f;
  unsigned u = v.u + 0x7FFFu + ((v.u >> 16) & 1u);
  return (ushort)(u >> 16);
}
__device__ __forceinline__ float bf2f(ushort h) {
  union { unsigned u; float f; } v; v.u = ((unsigned)h) << 16;
  return v.f;
}
__device__ __forceinline__ void gload_lds16(const ushort* g, ushort* l) {
  __builtin_amdgcn_global_load_lds((const __attribute__((address_space(1))) void*)g,
                                   (__attribute__((address_space(3))) void*)l, 16, 0, 0);
}

// ---------------------------------------------------------------- prep: casts + packing
__global__ __launch_bounds__(256) void prep_kernel(
    const float* __restrict__ hs, const float* __restrict__ qw,
    const float* __restrict__ kw, const float* __restrict__ vw,
    const float* __restrict__ ow, const float* __restrict__ qb,
    const float* __restrict__ kb, const float* __restrict__ vb,
    ushort* __restrict__ hs_b, ushort* __restrict__ qkvw_b,
    ushort* __restrict__ ow_b, float* __restrict__ qkvb)
{
  const int idx = blockIdx.x * 256 + threadIdx.x;
  const int stride = gridDim.x * 256;
  const float4* hs4 = (const float4*)hs;
  const float4* qw4 = (const float4*)qw;
  const float4* kw4 = (const float4*)kw;
  const float4* vw4 = (const float4*)vw;
  const float4* ow4 = (const float4*)ow;
  ushort4* hsb4 = (ushort4*)hs_b;
  ushort4* qkvwb4 = (ushort4*)qkvw_b;
  ushort4* owb4 = (ushort4*)ow_b;

  for (int i = idx; i < 2097152; i += stride) {
    float4 v = hs4[i];
    ushort4 o; o.x=f2bf(v.x); o.y=f2bf(v.y); o.z=f2bf(v.z); o.w=f2bf(v.w);
    hsb4[i] = o;
  }
  for (int i = idx; i < 1048576; i += stride) {
    float4 v = qw4[i];
    ushort4 o; o.x=f2bf(v.x); o.y=f2bf(v.y); o.z=f2bf(v.z); o.w=f2bf(v.w);
    qkvwb4[i] = o;
  }
  for (int i = idx; i < 262144; i += stride) {
    float4 v = kw4[i];
    ushort4 o; o.x=f2bf(v.x); o.y=f2bf(v.y); o.z=f2bf(v.z); o.w=f2bf(v.w);
    qkvwb4[1048576 + i] = o;
  }
  for (int i = idx; i < 262144; i += stride) {
    float4 v = vw4[i];
    ushort4 o; o.x=f2bf(v.x); o.y=f2bf(v.y); o.z=f2bf(v.z); o.w=f2bf(v.w);
    qkvwb4[1310720 + i] = o;
  }
  for (int i = idx; i < 1048576; i += stride) {
    float4 v = ow4[i];
    ushort4 o; o.x=f2bf(v.x); o.y=f2bf(v.y); o.z=f2bf(v.z); o.w=f2bf(v.w);
    owb4[i] = o;
  }
  for (int i = idx; i < 3072; i += stride)
    qkvb[i] = (i < 2048) ? qb[i] : (i < 2560 ? kb[i - 2048] : vb[i - 2560]);
}

// ---------------------------------------------------------------- GEMM: C = A(MxK) * Bw(NxK)^T + bias
// Cols >= vsplit go transposed to vt[(col-vsplit)*4096 + row] (V pre-transpose for flash).
template<int BF16OUT>
__global__ __launch_bounds__(256) void gemm_bt(
    const ushort* __restrict__ A, const ushort* __restrict__ Bw,
    const float* __restrict__ bias, void* __restrict__ Cout,
    ushort* __restrict__ vt,
    int M, int N, int K, int ldc, int vsplit)
{
  __shared__ ushort As[128 * 32];
  __shared__ ushort Bs[128 * 32];
  const int t = threadIdx.x;
  const int wv = t >> 6;
  const int lane = t & 63;
  const int qd = lane >> 4, ln = lane & 15;
  const long row0 = (long)blockIdx.x * 128, col0 = (long)blockIdx.y * 128;
  const int wm = (wv >> 1) * 64, wn = (wv & 1) * 64;

  f32x4 acc[4][4];
#pragma unroll
  for (int i = 0; i < 4; i++)
#pragma unroll
    for (int j = 0; j < 4; j++) acc[i][j] = (f32x4){0.f, 0.f, 0.f, 0.f};

  const ushort* gA = A + (row0 + (t >> 2)) * (long)K + (t & 3) * 8;
  const ushort* gB = Bw + (col0 + (t >> 2)) * (long)K + (t & 3) * 8;
  ushort* lA = &As[wv * 512];
  ushort* lB = &Bs[wv * 512];
  const long K64 = 64l * K;

  for (int kt = 0; kt < K; kt += 32) {
    __syncthreads();
    gload_lds16(gA + kt,        lA);
    gload_lds16(gA + kt + K64,  lA + 2048);
    gload_lds16(gB + kt,        lB);
    gload_lds16(gB + kt + K64,  lB + 2048);
    __syncthreads();
    bf16x8 af[4], bf[4];
#pragma unroll
    for (int mi = 0; mi < 4; mi++)
      af[mi] = *(const bf16x8*)&As[(wm + mi * 16 + ln) * 32 + qd * 8];
#pragma unroll
    for (int ni = 0; ni < 4; ni++)
      bf[ni] = *(const bf16x8*)&Bs[(wn + ni * 16 + ln) * 32 + qd * 8];
#pragma unroll
    for (int mi = 0; mi < 4; mi++)
#pragma unroll
      for (int ni = 0; ni < 4; ni++)
        acc[mi][ni] = __builtin_amdgcn_mfma_f32_16x16x32_bf16(af[mi], bf[ni], acc[mi][ni], 0, 0, 0);
  }

  float bv[4];
#pragma unroll
  for (int ni = 0; ni < 4; ni++) bv[ni] = bias[col0 + wn + ni * 16 + ln];

  if (col0 >= vsplit) {
    // V part: write transposed vt[(col - vsplit)][row], row-stride 4096
#pragma unroll
    for (int mi = 0; mi < 4; mi++)
#pragma unroll
      for (int ni = 0; ni < 4; ni++)
#pragma unroll
        for (int r = 0; r < 4; r++) {
          long row = row0 + wm + mi * 16 + qd * 4 + r;
          long col = col0 + wn + ni * 16 + ln - vsplit;
          vt[col * 4096 + row] = f2bf(acc[mi][ni][r] + bv[ni]);
        }
  } else {
#pragma unroll
    for (int mi = 0; mi < 4; mi++)
#pragma unroll
      for (int ni = 0; ni < 4; ni++)
#pragma unroll
        for (int r = 0; r < 4; r++) {
          long row = row0 + wm + mi * 16 + qd * 4 + r;
          long col = col0 + wn + ni * 16 + ln;
          float v = acc[mi][ni][r] + bv[ni];
          if (BF16OUT) ((ushort*)Cout)[row * ldc + col] = f2bf(v);
          else         ((float*)Cout)[row * ldc + col] = v;
        }
  }
}

// ---------------------------------------------------------------- RoPE in place on Q/K (qk buffer, ld=2560)
// 1/sqrt(128) folded into cos/sin for Q heads.
__global__ __launch_bounds__(256) void rope_kernel(ushort* __restrict__ qk)
{
  const int i = blockIdx.x * 256 + threadIdx.x;   // 4096 rows * 20 heads * 64 pairs
  if (i >= 5242880) return;
  const int pair = i & 63;
  const int head = (i >> 6) % 20;
  const int row  = (i >> 6) / 20;
  const int pos  = row & 2047;
  const int base = head < 16 ? head * 128 : 2048 + (head - 16) * 128;
  ushort* p = qk + (long)row * 2560 + base + pair;
  const float v0 = bf2f(p[0]);
  const float v1 = bf2f(p[64]);
  const float inv = expf((float)pair * -0.14391156831212787f);
  const float ang = (float)pos * inv;
  const float sc = (head < 16) ? 0.08838834764831845f : 1.0f;  // fold 1/sqrt(d) into Q
  const float c = cosf(ang) * sc, s = sinf(ang) * sc;
  p[0]  = f2bf(v0 * c - v1 * s);
  p[64] = f2bf(v1 * c + v0 * s);
}

// ---------------------------------------------------------------- flash attention, BM=64, BN=64, HD=128
// qk: [4096][2560] bf16 (Q heads 0..15, K heads at 2048+). vt: [4 kvh][128 d][4096 tok] bf16.
__global__ __launch_bounds__(256) void flash_kernel(
    const ushort* __restrict__ qk, const ushort* __restrict__ vt,
    ushort* __restrict__ ctx)
{
  __shared__ ushort Qs[64 * 136];   // Q staging; reused as Ps (64 x 72) after Q-frag load
  __shared__ ushort Ks[64 * 136];   // K tile, row-major [kpos][d]
  __shared__ ushort Vts[128 * 72];  // V tile, transposed [d][kpos], stride 72 (144B = 16B-aligned rows)
  ushort* Ps = Qs;

  const int t = threadIdx.x, wv = t >> 6, lane = t & 63;
  const int qd = lane >> 4, ln = lane & 15;
  const int q0 = blockIdx.x * 64;
  const int b = blockIdx.y >> 4, h = blockIdx.y & 15;
  const long rb = (long)b * 2048;
  const ushort* Qg = qk + (rb + q0) * 2560 + h * 128;
  const ushort* Kg = qk + rb * 2560 + 2048 + (h >> 2) * 128;
  const ushort* Vtg = vt + ((long)(h >> 2) * 128) * 4096 + rb;

  const int sr = t >> 4;          // 0..15
  const int sc = (t & 15) * 8;    // 0..120

  // stage Q -> LDS, then pull the wave's A-frags into registers
#pragma unroll
  for (int i = 0; i < 4; i++) {
    int row = i * 16 + sr;
    *(uint4*)&Qs[row * 136 + sc] = *(const uint4*)(Qg + (long)row * 2560 + sc);
  }
  __syncthreads();
  bf16x8 aq[4];
#pragma unroll
  for (int ks = 0; ks < 4; ks++)
    aq[ks] = *(const bf16x8*)&Qs[(wv * 16 + ln) * 136 + ks * 32 + qd * 8];
  // NOTE: loop's leading __syncthreads() guards the Qs->Ps reuse.

  f32x4 oacc[8];
#pragma unroll
  for (int ni = 0; ni < 8; ni++) oacc[ni] = (f32x4){0.f, 0.f, 0.f, 0.f};
  float m_i[4] = {-INFINITY, -INFINITY, -INFINITY, -INFINITY};
  float l_i[4] = {0.f, 0.f, 0.f, 0.f};

  const int vd = t >> 3;          // 0..31 (d row block)
  const int vseg = (t & 7) * 8;   // 0..56 (kpos segment)

  for (int kt = 0; kt < 2048; kt += 64) {
    __syncthreads();
    // K tile: row-major copy (conflict-free b128 writes)
#pragma unroll
    for (int i = 0; i < 4; i++) {
      int row = i * 16 + sr;
      *(uint4*)&Ks[row * 136 + sc] = *(const uint4*)(Kg + (long)(kt + row) * 2560 + sc);
    }
    // V tile: already transposed in global -> row-major copy into Vts[d][kpos]
#pragma unroll
    for (int i = 0; i < 4; i++) {
      int d = i * 32 + vd;
      *(uint4*)&Vts[d * 72 + vseg] = *(const uint4*)(Vtg + (long)d * 4096 + kt + vseg);
    }
    __syncthreads();

    // S = Q K^T (wave's 16 q-rows x 64 kpos); Q frags in registers
    f32x4 sacc[4];
#pragma unroll
    for (int ni = 0; ni < 4; ni++) sacc[ni] = (f32x4){0.f, 0.f, 0.f, 0.f};
#pragma unroll
    for (int ks = 0; ks < 4; ks++) {
#pragma unroll
      for (int ni = 0; ni < 4; ni++) {
        bf16x8 bk = *(const bf16x8*)&Ks[(ni * 16 + ln) * 136 + ks * 32 + qd * 8];
        sacc[ni] = __builtin_amdgcn_mfma_f32_16x16x32_bf16(aq[ks], bk, sacc[ni], 0, 0, 0);
      }
    }

    // online softmax (rows = qd*4+r, cols = ni*16+ln); scale pre-folded into Q
    float alpha[4];
#pragma unroll
    for (int r = 0; r < 4; r++) {
      float mx = fmaxf(fmaxf(sacc[0][r], sacc[1][r]), fmaxf(sacc[2][r], sacc[3][r]));
      mx = fmaxf(mx, __shfl_xor(mx, 1, 64));
      mx = fmaxf(mx, __shfl_xor(mx, 2, 64));
      mx = fmaxf(mx, __shfl_xor(mx, 4, 64));
      mx = fmaxf(mx, __shfl_xor(mx, 8, 64));
      float mn = fmaxf(m_i[r], mx);
      float al = __expf(m_i[r] - mn);
      float rs = 0.f;
#pragma unroll
      for (int ni = 0; ni < 4; ni++) {
        float pv = __expf(sacc[ni][r] - mn);
        sacc[ni][r] = pv;
        rs += pv;
      }
      rs += __shfl_xor(rs, 1, 64);
      rs += __shfl_xor(rs, 2, 64);
      rs += __shfl_xor(rs, 4, 64);
      rs += __shfl_xor(rs, 8, 64);
      l_i[r] = l_i[r] * al + rs;
      m_i[r] = mn;
      alpha[r] = al;
    }
    // skip O-rescale when no row's max moved (alpha == 1 exactly)
    bool need = (alpha[0] < 1.f) | (alpha[1] < 1.f) | (alpha[2] < 1.f) | (alpha[3] < 1.f);
    if (__any(need)) {
#pragma unroll
      for (int ni = 0; ni < 8; ni++)
#pragma unroll
        for (int r = 0; r < 4; r++) oacc[ni][r] *= alpha[r];
    }

    // P -> LDS (C-layout write, own wave rows only), stride 72
#pragma unroll
    for (int ni = 0; ni < 4; ni++)
#pragma unroll
      for (int r = 0; r < 4; r++)
        Ps[(wv * 16 + qd * 4 + r) * 72 + ni * 16 + ln] = f2bf(sacc[ni][r]);

    // O += P V   (A = P 16x64 via b128, B = Vts[d][kpos] via b128, both conflict-free)
#pragma unroll
    for (int ks2 = 0; ks2 < 2; ks2++) {
      bf16x8 ap = *(const bf16x8*)&Ps[(wv * 16 + ln) * 72 + ks2 * 32 + qd * 8];
#pragma unroll
      for (int ni = 0; ni < 8; ni++) {
        bf16x8 bv = *(const bf16x8*)&Vts[(ni * 16 + ln) * 72 + ks2 * 32 + qd * 8];
        oacc[ni] = __builtin_amdgcn_mfma_f32_16x16x32_bf16(ap, bv, oacc[ni], 0, 0, 0);
      }
    }
  }

  const long orow = rb + q0 + wv * 16;
#pragma unroll
  for (int ni = 0; ni < 8; ni++)
#pragma unroll
    for (int r = 0; r < 4; r++) {
      float v = oacc[ni][r] / (l_i[r] + 1e-10f);
      ctx[(orow + qd * 4 + r) * 2048 + h * 128 + ni * 16 + ln] = f2bf(v);
    }
}

// ---------------------------------------------------------------- launch
extern "C" void kernel_launch(void* const* d_in, const int* in_sizes, int n_in,
                              void* d_out, int out_size, void* d_ws, size_t ws_size,
                              hipStream_t stream)
{
  const float* hs = (const float*)d_in[0];
  const float* qw = (const float*)d_in[1];
  const float* qb = (const float*)d_in[2];
  const float* kw = (const float*)d_in[3];
  const float* kb = (const float*)d_in[4];
  const float* vw = (const float*)d_in[5];
  const float* vb = (const float*)d_in[6];
  const float* ow = (const float*)d_in[7];
  const float* ob = (const float*)d_in[8];

  char* ws = (char*)d_ws;
  ushort* hs_b   = (ushort*)(ws);                 // 16,777,216 B
  ushort* qkvw_b = (ushort*)(ws + 16777216);      // 12,582,912 B
  ushort* ow_b   = (ushort*)(ws + 29360128);      //  8,388,608 B
  float*  qkvb   = (float*) (ws + 37748736);      //     12,288 B
  ushort* qkbuf  = (ushort*)(ws + 37761024);      // 20,971,520 B  [4096][2560]
  ushort* vtbuf  = (ushort*)(ws + 58732544);      //  4,194,304 B  [4*128][4096]
  ushort* ctx    = (ushort*)(ws + 62926848);      // 16,777,216 B  (total 79,704,064 — same as R1)

  prep_kernel<<<1024, 256, 0, stream>>>(hs, qw, kw, vw, ow, qb, kb, vb,
                                        hs_b, qkvw_b, ow_b, qkvb);
  gemm_bt<1><<<dim3(32, 24), 256, 0, stream>>>(hs_b, qkvw_b, qkvb, qkbuf, vtbuf,
                                               4096, 3072, 2048, 2560, 2560);
  rope_kernel<<<20480, 256, 0, stream>>>(qkbuf);
  flash_kernel<<<dim3(32, 32), 256, 0, stream>>>(qkbuf, vtbuf, ctx);
  gemm_bt<0><<<dim3(32, 16), 256, 0, stream>>>(ctx, ow_b, ob, d_out, nullptr,
                                               4096, 2048, 2048, 2048, 1 << 30);
}